// Round 3
// baseline (367.773 us; speedup 1.0000x reference)
//
#include <hip/hip_runtime.h>
#include <cstdint>

// LSTM cell: B=8192, DIM_IN=1024, DIM_OUT=1024, d=2048
// gates = [X|H][8192,2048] @ W[2048,4096] + b ; epilogue fused into GEMM.
// R2: BK=64 (halves barrier count vs BK=32; LDS 32 KB keeps 5 blocks/CU),
// 64x64 wave tiles, fast exp2/rcp activations, vectorized preps.
// W pre-permuted: n'' = (j>>4)*64 + g*16 + (j&15) so each wave's 64 cols =
// 16 j-columns x all 4 gates (in-register LSTM epilogue, gates never hit HBM).

#define B_ROWS 8192
#define DK 2048
#define DOUT 1024
#define TM 128
#define TN 128
#define BK 64

typedef __bf16 bf16x8 __attribute__((ext_vector_type(8)));
typedef __bf16 bf16x4 __attribute__((ext_vector_type(4)));
typedef float f32x4 __attribute__((ext_vector_type(4)));

__device__ inline void load16_to_lds(const __bf16* gsrc, __bf16* ldst) {
    __builtin_amdgcn_global_load_lds(
        (const __attribute__((address_space(1))) void*)gsrc,
        (__attribute__((address_space(3))) void*)ldst,
        16, 0, 0);
}

__device__ inline float fast_sigmoid(float x) {
    return __builtin_amdgcn_rcpf(1.0f + __builtin_amdgcn_exp2f(-1.442695041f * x));
}
__device__ inline float fast_tanh(float x) {
    return 1.0f - 2.0f * __builtin_amdgcn_rcpf(1.0f + __builtin_amdgcn_exp2f(2.885390082f * x));
}

// ---- prep 1: X = bf16(concat(x,h)) [8192][2048]; 8 elems/thread, 16B writes
__global__ __launch_bounds__(256) void prep_x(const float* __restrict__ x,
                                              const float* __restrict__ h,
                                              __bf16* __restrict__ X) {
    int id = blockIdx.x * 256 + threadIdx.x;   // 0 .. 8192*256-1
    int b = id >> 8;            // 256 8-elem groups per 2048-row
    int k = (id & 255) * 8;     // multiple of 8: never straddles 1024 boundary
    const float* src = (k < 1024) ? &x[(size_t)b * 1024 + k]
                                  : &h[(size_t)b * 1024 + (k - 1024)];
    float4 v0 = *(const float4*)src;
    float4 v1 = *(const float4*)(src + 4);
    bf16x8 o = { (__bf16)v0.x, (__bf16)v0.y, (__bf16)v0.z, (__bf16)v0.w,
                 (__bf16)v1.x, (__bf16)v1.y, (__bf16)v1.z, (__bf16)v1.w };
    *(bf16x8*)&X[(size_t)b * 2048 + k] = o;
}

// ---- prep 2: Wt[n''][k] = bf16(W_g[k][j]); n'' = (j>>4)*64 + g*16 + (j&15)
// 64k x 32j tiles -> 128 B k-contiguous write segments per n'' row.
__global__ __launch_bounds__(256) void prep_w(const float* __restrict__ WI,
                                              const float* __restrict__ WF,
                                              const float* __restrict__ WG,
                                              const float* __restrict__ WO,
                                              __bf16* __restrict__ Wt) {
    int kb = blockIdx.x;       // 0..31 (k tiles of 64)
    int jb = blockIdx.y;       // 0..31 (j tiles of 32)
    int j0 = jb * 32;
    __shared__ float t[64][33];
    int tx = threadIdx.x, ty = threadIdx.y;   // block (32,8)
    int idx = ty * 32 + tx;                   // 0..255
    const float* Ws[4] = {WI, WF, WG, WO};
#pragma unroll
    for (int g = 0; g < 4; ++g) {
        const float* W = Ws[g];
#pragma unroll
        for (int yy = 0; yy < 64; yy += 8) {
            int k = kb * 64 + ty + yy;
            t[ty + yy][tx] = W[(size_t)k * 1024 + j0 + tx];
        }
        __syncthreads();
#pragma unroll
        for (int w = 0; w < 2; ++w) {
            int slot = w * 256 + idx;         // 0..511
            int r = slot >> 4;                // j within tile, 0..31
            int k0 = (slot & 15) * 4;         // k offset within 64
            bf16x4 o = { (__bf16)t[k0 + 0][r], (__bf16)t[k0 + 1][r],
                         (__bf16)t[k0 + 2][r], (__bf16)t[k0 + 3][r] };
            int npp = (jb * 2 + (r >> 4)) * 64 + g * 16 + (r & 15);
            *(bf16x4*)&Wt[(size_t)npp * 2048 + kb * 64 + k0] = o;
        }
        __syncthreads();
    }
}

// ---- fused GEMM + LSTM epilogue ----
__global__ __launch_bounds__(256) void lstm_gemm(
    const __bf16* __restrict__ Xbf, const __bf16* __restrict__ Wt,
    const float* __restrict__ c,
    const float* __restrict__ bI, const float* __restrict__ bF,
    const float* __restrict__ bG, const float* __restrict__ bO,
    float* __restrict__ outH, float* __restrict__ outC)
{
    __shared__ __bf16 As[TM * BK];   // [row][k] 128x64 = 16 KB
    __shared__ __bf16 Bs[TN * BK];   // [n''][k] 128x64 = 16 KB

    const int t = threadIdx.x;
    const int lane = t & 63;
    const int wave = t >> 6;
    const int wm = wave >> 1;         // 2x2 waves of 64x64
    const int wn = wave & 1;
    const int m0 = blockIdx.x * TM;   // 64 blocks in M
    const int nb = blockIdx.y;        // 32 blocks in N
    const int n0 = nb * TN;

    f32x4 acc[4][4];
#pragma unroll
    for (int i = 0; i < 4; ++i)
#pragma unroll
        for (int j = 0; j < 4; ++j) acc[i][j] = (f32x4){0.f, 0.f, 0.f, 0.f};

    // staging: 128 rows x 64 k x 2B = 16 KB = 1024 x 16B chunks; 4/thread.
    // chunk ci = q*256 + t : row = ci>>3, kc = (ci&7)*8
    const int rs = t >> 3;            // 0..31 row sub-index
    const int kc = (t & 7) * 8;
    const __bf16* gA = Xbf + (size_t)(m0 + rs) * DK + kc;
    const __bf16* gB = Wt + (size_t)(n0 + rs) * DK + kc;
    // wave-uniform LDS bases (HW adds lane*16 bytes); q chunk-group offset:
    // elements: q*2048 + wave*512
    __bf16* lA = As + wave * 512;
    __bf16* lB = Bs + wave * 512;

    const int lr = lane & 15;
    const int kh = (lane >> 4) * 8;
    const int arow = wm * 64 + lr;
    const int brow = wn * 64 + lr;

    for (int kk = 0; kk < DK / BK; ++kk) {
#pragma unroll
        for (int q = 0; q < 4; ++q) {
            load16_to_lds(gA + (size_t)(q * 32) * DK, lA + q * 2048);
            load16_to_lds(gB + (size_t)(q * 32) * DK, lB + q * 2048);
        }
        gA += BK; gB += BK;
        __syncthreads();   // drains vmcnt before barrier

#pragma unroll
        for (int ks = 0; ks < BK; ks += 32) {
            bf16x8 a[4], b[4];
#pragma unroll
            for (int i = 0; i < 4; ++i)
                a[i] = *(const bf16x8*)&As[(arow + i * 16) * BK + ks + kh];
#pragma unroll
            for (int j = 0; j < 4; ++j)
                b[j] = *(const bf16x8*)&Bs[(brow + j * 16) * BK + ks + kh];
#pragma unroll
            for (int i = 0; i < 4; ++i)
#pragma unroll
                for (int j = 0; j < 4; ++j)
                    acc[i][j] = __builtin_amdgcn_mfma_f32_16x16x32_bf16(a[i], b[j], acc[i][j], 0, 0, 0);
        }
        __syncthreads();
    }

    // epilogue: C/D layout col=lane&15, row=(lane>>4)*4+reg; acc[i][g] = gate g
    const int col = lane & 15;
    const int j = (nb * 2 + wn) * 16 + col;     // original gate column
    const float biI = bI[j], biF = bF[j], biG = bG[j], biO = bO[j];
    const int rbase = m0 + wm * 64 + (lane >> 4) * 4;
#pragma unroll
    for (int i = 0; i < 4; ++i) {
#pragma unroll
        for (int r = 0; r < 4; ++r) {
            int row = rbase + i * 16 + r;
            float I = fast_sigmoid(acc[i][0][r] + biI);
            float F = fast_sigmoid(acc[i][1][r] + biF);
            float G = fast_tanh(acc[i][2][r] + biG);
            float O = fast_sigmoid(acc[i][3][r] + biO);
            size_t idx = (size_t)row * DOUT + j;
            float Cn = F * c[idx] + I * G;
            outH[idx] = O * fast_tanh(Cn);
            outC[idx] = Cn;
        }
    }
}

extern "C" void kernel_launch(void* const* d_in, const int* in_sizes, int n_in,
                              void* d_out, int out_size, void* d_ws, size_t ws_size,
                              hipStream_t stream) {
    const float* x  = (const float*)d_in[0];
    const float* h  = (const float*)d_in[1];
    const float* c  = (const float*)d_in[2];
    const float* WI = (const float*)d_in[3];
    const float* bI = (const float*)d_in[4];
    const float* WF = (const float*)d_in[5];
    const float* bF = (const float*)d_in[6];
    const float* WG = (const float*)d_in[7];
    const float* bG = (const float*)d_in[8];
    const float* WO = (const float*)d_in[9];
    const float* bO = (const float*)d_in[10];

    __bf16* Xbf = (__bf16*)d_ws;                                    // 32 MB
    __bf16* Wt  = (__bf16*)((char*)d_ws + (size_t)B_ROWS * DK * 2); // 16 MB
    float* outH = (float*)d_out;
    float* outC = outH + (size_t)B_ROWS * DOUT;

    prep_x<<<(B_ROWS * DK / 8) / 256, 256, 0, stream>>>(x, h, Xbf);
    prep_w<<<dim3(DK / 64, DOUT / 32), dim3(32, 8), 0, stream>>>(WI, WF, WG, WO, Wt);
    lstm_gemm<<<dim3(B_ROWS / TM, 4 * DOUT / TN), 256, 0, stream>>>(
        Xbf, Wt, c, bI, bF, bG, bO, outH, outC);
}